// Round 11
// baseline (225.404 us; speedup 1.0000x reference)
//
#include <hip/hip_runtime.h>
#include <hip/hip_bf16.h>

// ---------------------------------------------------------------------------
// 2-layer GraphConv (DGL norm='both') + mean_nodes pool + linear classifier.
// N=80000, E=1.28M, D=H=64, C=5, G=512.
// R22: agg (~38-40us x2) was LDS-PIPE-heavy: per node ~8 ds_bpermute (index
// shfl) + 24 butterfly shfl_xor + 4 prefetch shfl = 36 LDS ops/node ->
// 312 nodes/CU x 36 x 5.8cyc ~= 27us/CU serialized on the LDS pipe (same
// failure mode as R13's GEMV). REWRITE the lane mapping so the reduction
// disappears: lane l owns output column l (64 lanes x 2B = exactly one 128B
// row per edge);
//  - edge-index broadcast via __builtin_amdgcn_readlane(cur, e): loop counter
//    is wave-uniform -> SALU, ZERO LDS-pipe ops (vs ds_bpermute);
//  - acc += bf1(z[idx*64+lane]): 2 VALU/edge, NO butterfly;
//  - store: 64 lanes x ushort = coalesced 128B, no pack shuffles.
// Per node: LDS ops 36 -> 0, VALU ~130 -> ~40, loads in flight 4 -> 8,
// VGPR ~68 -> ~30. Memory traffic identical (1 line per edge either way).
// pA / p5 / gemm / cls are R18-exact (R21-verbatim).
// ---------------------------------------------------------------------------

#define NBK 160            // max buckets: ceil(80000/512)=157 <= 160
#define HB  256            // edge-pass blocks in pA
#define CAP 9216           // per-bucket slot capacity (mean 8192, +11 sigma)

typedef __attribute__((ext_vector_type(8))) short bf16x8;
typedef __attribute__((ext_vector_type(4))) float f32x4;

__device__ __forceinline__ float bflo(unsigned u) { return __uint_as_float(u << 16); }
__device__ __forceinline__ float bfhi(unsigned u) { return __uint_as_float(u & 0xffff0000u); }
__device__ __forceinline__ float bf1(unsigned short u) { return __uint_as_float((unsigned)u << 16); }
__device__ __forceinline__ unsigned short f2bf(float f) {   // RNE
    unsigned u = __float_as_uint(f);
    return (unsigned short)((u + 0x7fff + ((u >> 16) & 1)) >> 16);
}

// --- pA: single-pass bucket scatter (blocks < HB) + graph bounds (rest) ----
__global__ __launch_bounds__(256) void pA_scatter(
    const int* __restrict__ src, const int* __restrict__ dst,
    int* __restrict__ curD, int* __restrict__ curS,       // NBK cursors each, pre-zeroed
    int* __restrict__ pack, unsigned short* __restrict__ sloc,
    const int* __restrict__ gids, int* __restrict__ goffs,
    int E, int NB, int N, int G)
{
    if (blockIdx.x >= HB) {                  // fused bounds_kernel
        int i = (blockIdx.x - HB) * 256 + threadIdx.x;
        if (i >= N) return;
        int b = gids[i];
        if (i == 0) {
            for (int g = 0; g <= b; g++) goffs[g] = 0;
        } else {
            int a = gids[i - 1];
            for (int g = a + 1; g <= b; g++) goffs[g] = i;
        }
        if (i == N - 1) {
            for (int g = b + 1; g <= G; g++) goffs[g] = N;
        }
        return;
    }
    __shared__ int hd[NBK], hs[NBK];
    int t = threadIdx.x;
    for (int i = t; i < NB; i += 256) { hd[i] = 0; hs[i] = 0; }
    __syncthreads();
    int chunk = (E + HB - 1) / HB;
    int s0 = blockIdx.x * chunk, s1 = min(E, s0 + chunk);
    // vectorized histogram pass
    int q0 = s0 >> 2, q1 = s1 >> 2;          // s0 is 4-aligned (chunk%4==0)
    const int4* s4 = (const int4*)src;
    const int4* d4 = (const int4*)dst;
    for (int q = q0 + t; q < q1; q += 256) {
        int4 d = d4[q];
        int4 s = s4[q];
        atomicAdd(&hd[d.x >> 9], 1); atomicAdd(&hd[d.y >> 9], 1);
        atomicAdd(&hd[d.z >> 9], 1); atomicAdd(&hd[d.w >> 9], 1);
        atomicAdd(&hs[s.x >> 9], 1); atomicAdd(&hs[s.y >> 9], 1);
        atomicAdd(&hs[s.z >> 9], 1); atomicAdd(&hs[s.w >> 9], 1);
    }
    for (int i = (q1 << 2) + t; i < s1; i += 256) {   // tail
        atomicAdd(&hd[dst[i] >> 9], 1);
        atomicAdd(&hs[src[i] >> 9], 1);
    }
    __syncthreads();
    for (int b = t; b < NB; b += 256) {      // reserve global slots
        int cd = hd[b], cs = hs[b];
        hd[b] = cd ? atomicAdd(&curD[b], cd) : 0;   // device atomic, 1/bucket
        hs[b] = cs ? atomicAdd(&curS[b], cs) : 0;
    }
    __syncthreads();
    // vectorized scatter pass (chunk re-read is L2-hot)
    for (int q = q0 + t; q < q1; q += 256) {
        int4 d = d4[q];
        int4 s = s4[q];
        #pragma unroll
        for (int j = 0; j < 4; j++) {
            int ss = j == 0 ? s.x : j == 1 ? s.y : j == 2 ? s.z : s.w;
            int dd = j == 0 ? d.x : j == 1 ? d.y : j == 2 ? d.z : d.w;
            int bd = dd >> 9, bs = ss >> 9;
            int pd = atomicAdd(&hd[bd], 1);  // LDS atomic
            int ps = atomicAdd(&hs[bs], 1);  // LDS atomic
            if (pd < CAP) pack[(size_t)bd * CAP + pd] = ((dd & 511) << 17) | ss;
            if (ps < CAP) sloc[(size_t)bs * CAP + ps] = (unsigned short)(ss & 511);
        }
    }
    for (int i = (q1 << 2) + t; i < s1; i += 256) {   // tail
        int s = src[i], d = dst[i];
        int bd = d >> 9, bs = s >> 9;
        int pd = atomicAdd(&hd[bd], 1);
        int ps = atomicAdd(&hs[bs], 1);
        if (pd < CAP) pack[(size_t)bd * CAP + pd] = ((d & 511) << 17) | s;
        if (ps < CAP) sloc[(size_t)bs * CAP + ps] = (unsigned short)(s & 511);
    }
}

// --- p5: dst mode -> CSR (row_offs,deg,col,ndst); src mode -> nsrc+prescale -
__global__ __launch_bounds__(256) void p5_build(
    const int* __restrict__ pack, const unsigned short* __restrict__ sloc,
    const int* __restrict__ curD, const int* __restrict__ curS,
    int* __restrict__ col, int* __restrict__ row_offs, int* __restrict__ deg,
    float* __restrict__ nsrc, float* __restrict__ ndst,
    const float* __restrict__ h, unsigned short* __restrict__ xs,
    int N, int NB)
{
    __shared__ int hist[512];
    __shared__ float nsl[512];
    __shared__ int wt[4];
    int t = threadIdx.x;
    bool dmode = blockIdx.x < NB;
    int b = dmode ? blockIdx.x : blockIdx.x - NB;
    int n0 = b << 9, n1 = min(N, n0 + 512);
    hist[t] = 0; hist[t + 256] = 0;
    __syncthreads();
    int e0 = b * CAP;
    int tot = min(dmode ? curD[b] : curS[b], CAP);
    int e1 = e0 + tot;
    if (!dmode) {
        for (int i = e0 + t; i < e1; i += 256)
            atomicAdd(&hist[sloc[i]], 1);            // LDS atomic
        __syncthreads();
        for (int n = n0 + t; n < n1; n += 256) {
            float s = rsqrtf((float)max(hist[n - n0], 1));
            nsrc[n] = s;
            nsl[n - n0] = s;
        }
        __syncthreads();
        int cnt = n1 - n0;
        const float2* h2p = (const float2*)h;
        ushort2* xp = (ushort2*)xs;
        for (int i = t; i < cnt * 32; i += 256) {
            int node = i >> 5;
            float s = nsl[node];
            float2 v = h2p[(size_t)(n0 + node) * 32 + (i & 31)];
            ushort2 o;
            o.x = f2bf(v.x * s);
            o.y = f2bf(v.y * s);
            xp[(size_t)(n0 + node) * 32 + (i & 31)] = o;
        }
        return;
    }
    for (int i = e0 + t; i < e1; i += 256)
        atomicAdd(&hist[pack[i] >> 17], 1);          // LDS atomic
    __syncthreads();
    int c0 = hist[2 * t], c1 = hist[2 * t + 1];
    int v = c0 + c1;
    int lane = t & 63, w = t >> 6;
    int x = v;
    #pragma unroll
    for (int off = 1; off < 64; off <<= 1) {
        int y = __shfl_up(x, off);
        if (lane >= off) x += y;
    }
    if (lane == 63) wt[w] = x;
    __syncthreads();
    int bw = 0;
    for (int i = 0; i < w; i++) bw += wt[i];
    int excl = x - v + bw;
    int n = n0 + 2 * t;
    if (n < n1) {
        row_offs[n] = e0 + excl;
        deg[n] = c0;
        ndst[n] = rsqrtf((float)max(c0, 1));
    }
    if (n + 1 < n1) {
        row_offs[n + 1] = e0 + excl + c0;
        deg[n + 1] = c1;
        ndst[n + 1] = rsqrtf((float)max(c1, 1));
    }
    hist[2 * t] = excl;
    hist[2 * t + 1] = excl + c0;
    __syncthreads();
    for (int i = e0 + t; i < e1; i += 256) {
        int wd = pack[i];
        int pos = atomicAdd(&hist[wd >> 17], 1);     // LDS atomic
        col[e0 + pos] = wd & 0x1FFFF;
    }
}

// --- gather-sum, lane-per-column: zero LDS-pipe ops, readlane broadcasts ---
__global__ __launch_bounds__(256) void agg_kernel(
    const unsigned short* __restrict__ z, unsigned short* __restrict__ y,
    const int* __restrict__ col, const int* __restrict__ row_offs,
    const int* __restrict__ deg, int N)
{
    int lane = threadIdx.x & 63;

    int wid = (blockIdx.x * 256 + threadIdx.x) >> 6;
    int nw  = (gridDim.x * 256) >> 6;

    int ro = 0, cnt = 0, cidx = 0;
    if (wid < N) {
        ro = row_offs[wid];
        cnt = deg[wid];
        if (lane < min(cnt, 64)) cidx = col[ro + lane];
    }
    for (int node = wid; node < N; node += nw) {
        int nnode = node + nw;
        int nro = 0, ncnt = 0;
        if (nnode < N) { nro = row_offs[nnode]; ncnt = deg[nnode]; }  // prefetch

        float acc = 0.f;
        int cc = 0;
        int cur = cidx;
        while (cc < cnt) {
            int m = min(cnt - cc, 64);
            int e = 0;
            for (; e + 8 <= m; e += 8) {     // 8 independent lines in flight
                int s0 = __builtin_amdgcn_readlane(cur, e);
                int s1 = __builtin_amdgcn_readlane(cur, e + 1);
                int s2 = __builtin_amdgcn_readlane(cur, e + 2);
                int s3 = __builtin_amdgcn_readlane(cur, e + 3);
                int s4 = __builtin_amdgcn_readlane(cur, e + 4);
                int s5 = __builtin_amdgcn_readlane(cur, e + 5);
                int s6 = __builtin_amdgcn_readlane(cur, e + 6);
                int s7 = __builtin_amdgcn_readlane(cur, e + 7);
                unsigned short u0 = z[(size_t)s0 * 64 + lane];
                unsigned short u1 = z[(size_t)s1 * 64 + lane];
                unsigned short u2 = z[(size_t)s2 * 64 + lane];
                unsigned short u3 = z[(size_t)s3 * 64 + lane];
                unsigned short u4 = z[(size_t)s4 * 64 + lane];
                unsigned short u5 = z[(size_t)s5 * 64 + lane];
                unsigned short u6 = z[(size_t)s6 * 64 + lane];
                unsigned short u7 = z[(size_t)s7 * 64 + lane];
                float t0 = bf1(u0) + bf1(u1);
                float t1 = bf1(u2) + bf1(u3);
                float t2 = bf1(u4) + bf1(u5);
                float t3 = bf1(u6) + bf1(u7);
                acc += (t0 + t1) + (t2 + t3);
            }
            for (; e < m; e++) {             // tail (deg % 8)
                int s = __builtin_amdgcn_readlane(cur, e);
                acc += bf1(z[(size_t)s * 64 + lane]);
            }
            cc += 64;
            if (cc < cnt) cur = (lane < min(cnt - cc, 64)) ? col[ro + cc + lane] : 0;
        }

        // prefetch next node's col during the store
        cidx = 0;
        if (nnode < N && lane < min(ncnt, 64)) cidx = col[nro + lane];

        y[(size_t)node * 64 + lane] = f2bf(acc);   // 64 lanes, 128B coalesced
        ro = nro; cnt = ncnt;
    }
}

// --- GEMM + epilogue (R18-exact) -------------------------------------------
// POOL=0: Z[m] = bf16(relu(ndst[m]*(S[m]@W) + b) * nsrc[m])   (layer 1)
// POOL=1: pooled into gacc[graph][64]; wave-level pre-reduction (gids sorted:
//         one atomic per (wave,col) for single-graph waves; per-element
//         fallback at boundaries). NO fence, NO ticket.
template<int POOL>
__global__ __launch_bounds__(256) void gemm_kernel(
    const unsigned short* __restrict__ A, const float* __restrict__ W,
    const float* __restrict__ b, const float* __restrict__ ndst,
    const float* __restrict__ nsrc, unsigned short* __restrict__ Z,
    const int* __restrict__ gids, float* __restrict__ gacc, int M)
{
    int t = threadIdx.x, lane = t & 63, w = t >> 6;
    int col = lane & 15, quad = lane >> 4;
    bf16x8 bfrag[4][2];
    #pragma unroll
    for (int nt = 0; nt < 4; nt++)
        #pragma unroll
        for (int ks = 0; ks < 2; ks++)
            #pragma unroll
            for (int j = 0; j < 8; j++)
                bfrag[nt][ks][j] =
                    (short)f2bf(W[(ks * 32 + quad * 8 + j) * 64 + nt * 16 + col]);
    float bias[4];
    #pragma unroll
    for (int nt = 0; nt < 4; nt++) bias[nt] = b[nt * 16 + col];

    int mbase = blockIdx.x * 64 + w * 16;
    if (mbase >= M) return;                    // whole-wave exit, no barriers
    int row = min(mbase + col, M - 1);
    const uint4* a4 = (const uint4*)A;
    union { uint4 u; bf16x8 v; } a0, a1;
    a0.u = a4[(size_t)row * 8 + quad];
    a1.u = a4[(size_t)row * 8 + 4 + quad];

    float nd[4], ns[4];
    int gg[4];
    #pragma unroll
    for (int r = 0; r < 4; r++) {
        int m = min(mbase + quad * 4 + r, M - 1);
        nd[r] = ndst[m];
        ns[r] = POOL ? 1.f : nsrc[m];
        gg[r] = POOL ? gids[m] : 0;
    }
    bool uni = false;
    int g0 = 0;
    if (POOL) {
        g0 = gids[min(mbase, M - 1)];
        uni = (g0 == gids[min(mbase + 15, M - 1)]) && (mbase + 15 < M);
    }

    #pragma unroll
    for (int nt = 0; nt < 4; nt++) {
        f32x4 acc = {0.f, 0.f, 0.f, 0.f};
        acc = __builtin_amdgcn_mfma_f32_16x16x32_bf16(a0.v, bfrag[nt][0], acc, 0, 0, 0);
        acc = __builtin_amdgcn_mfma_f32_16x16x32_bf16(a1.v, bfrag[nt][1], acc, 0, 0, 0);
        if (POOL) {
            float vv[4];
            #pragma unroll
            for (int r = 0; r < 4; r++) {
                int m = mbase + quad * 4 + r;
                vv[r] = (m < M) ? fmaxf(nd[r] * acc[r] + bias[nt], 0.f) : 0.f;
            }
            if (uni) {                       // 16 rows, one graph: 1 atomic/col
                float s = (vv[0] + vv[1]) + (vv[2] + vv[3]);
                s += __shfl_xor(s, 16);
                s += __shfl_xor(s, 32);
                if (quad == 0)
                    atomicAdd(&gacc[(size_t)g0 * 64 + nt * 16 + col], s);
            } else {                         // boundary wave (rare)
                #pragma unroll
                for (int r = 0; r < 4; r++) {
                    int m = mbase + quad * 4 + r;
                    if (m < M)
                        atomicAdd(&gacc[(size_t)gg[r] * 64 + nt * 16 + col], vv[r]);
                }
            }
        } else {
            #pragma unroll
            for (int r = 0; r < 4; r++) {
                int m = mbase + quad * 4 + r;
                if (m < M) {
                    float v = fmaxf(nd[r] * acc[r] + bias[nt], 0.f);
                    Z[(size_t)m * 64 + nt * 16 + col] = f2bf(v * ns[r]);
                }
            }
        }
    }
}

// --- per-graph mean + 64x5 classifier (1 wave per graph) -------------------
__global__ __launch_bounds__(64) void cls_kernel(
    const float* __restrict__ gacc, const int* __restrict__ goffs,
    const float* __restrict__ Wc, const float* __restrict__ bc,
    float* __restrict__ out, int G)
{
    int g = blockIdx.x;
    int lane = threadIdx.x;
    float cnt = (float)max(goffs[g + 1] - goffs[g], 1);
    float mean = gacc[(size_t)g * 64 + lane] / cnt;
    #pragma unroll
    for (int c = 0; c < 5; c++) {
        float p = mean * Wc[lane * 5 + c];
        #pragma unroll
        for (int off = 32; off; off >>= 1) p += __shfl_down(p, off);
        if (lane == 0) out[g * 5 + c] = p + bc[c];
    }
}

extern "C" void kernel_launch(void* const* d_in, const int* in_sizes, int n_in,
                              void* d_out, int out_size, void* d_ws, size_t ws_size,
                              hipStream_t stream)
{
    const float* h    = (const float*)d_in[0];
    const int*   src  = (const int*)d_in[1];
    const int*   dst  = (const int*)d_in[2];
    const int*   gids = (const int*)d_in[3];
    const float* W1   = (const float*)d_in[4];
    const float* b1   = (const float*)d_in[5];
    const float* W2   = (const float*)d_in[6];
    const float* b2   = (const float*)d_in[7];
    const float* Wc   = (const float*)d_in[8];
    const float* bc   = (const float*)d_in[9];
    float* out = (float*)d_out;

    const int N = in_sizes[0] / 64;
    const int E = in_sizes[1];
    const int G = out_size / 5;
    const int NB = (N + 511) >> 9;
    const int NBB = (N + 255) / 256;        // bounds blocks

    auto align = [](size_t x) { return (x + 255) & ~(size_t)255; };
    char* p = (char*)d_ws;
    // curD | curS | gacc contiguous -> single memset clears all three
    int* curD    = (int*)p;
    int* curS    = curD + NBK;
    float* gacc  = (float*)(p + (size_t)2 * NBK * 4);   // G*64 floats
    size_t zbytes = (size_t)2 * NBK * 4 + (size_t)G * 64 * 4;
    p += align(zbytes);
    int* row_offs= (int*)p;            p += align((size_t)N * 4);
    int* deg     = (int*)p;            p += align((size_t)N * 4);
    float* nsrc  = (float*)p;          p += align((size_t)N * 4);
    float* ndst  = (float*)p;          p += align((size_t)N * 4);
    int* goffs   = (int*)p;            p += align((size_t)(G + 1) * 4);
    int* pack    = (int*)p;            p += align((size_t)NBK * CAP * 4);
    unsigned short* sloc = (unsigned short*)p; p += align((size_t)NBK * CAP * 2);
    int* cols    = (int*)p;            p += align((size_t)NBK * CAP * 4);
    unsigned short* xs  = (unsigned short*)p; p += align((size_t)N * 64 * 2);
    unsigned short* s1  = (unsigned short*)p; p += align((size_t)N * 64 * 2);
    unsigned short* h1s = (unsigned short*)p; p += align((size_t)N * 64 * 2);
    unsigned short* s2  = s1;   // alias: s1 dead after gemm1

    hipMemsetAsync(curD, 0, zbytes, stream);

    pA_scatter<<<HB + NBB, 256, 0, stream>>>(src, dst, curD, curS, pack, sloc,
                                             gids, goffs, E, NB, N, G);
    p5_build<<<2 * NB, 256, 0, stream>>>(pack, sloc, curD, curS, cols,
                                         row_offs, deg, nsrc, ndst, h, xs, N, NB);

    agg_kernel<<<4096, 256, 0, stream>>>(xs, s1, cols, row_offs, deg, N);
    gemm_kernel<0><<<(N + 63) / 64, 256, 0, stream>>>(s1, W1, b1, ndst, nsrc,
                                                      h1s, nullptr, nullptr, N);
    agg_kernel<<<4096, 256, 0, stream>>>(h1s, s2, cols, row_offs, deg, N);
    gemm_kernel<1><<<(N + 63) / 64, 256, 0, stream>>>(s2, W2, b2, ndst, nullptr,
                                                      nullptr, gids, gacc, N);
    cls_kernel<<<G, 64, 0, stream>>>(gacc, goffs, Wc, bc, out, G);
}

// Round 12
// 217.899 us; speedup vs baseline: 1.0344x; 1.0344x over previous
//
#include <hip/hip_runtime.h>
#include <hip/hip_bf16.h>

// ---------------------------------------------------------------------------
// 2-layer GraphConv (DGL norm='both') + mean_nodes pool + linear classifier.
// N=80000, E=1.28M, D=H=64, C=5, G=512.
// R23: FINAL REVERT to R18-exact (215.2us, the session best). Twelve rounds
// bracket the plateau: (1) grid.sync / per-block threadfence are 150-250us
// catastrophes on 8-XCD MI355X (R12/R20); (2) dispatch fission costs ~8us
// per extra launch (R19); (3) agg is latency-bound at ~38us/pass -- three
// independent restructurings (dual-node MLP R16, data-prefetch R20,
// lane-per-column readlane R22) all land within +-7us of the R11 form;
// (4) the one structural win since R11 was R18's wave-level pool
// pre-reduction in gemm<1> (5.12M -> ~0.8M device atomics, -75us).
// Remaining budget: agg 2x38 + pA/p5 ~45 (atomic-bound binning) + gemm ~22 +
// cls/memset ~10 + ~60us serialized dispatch overhead = ~215us. The kernel
// boundary IS the cheap global barrier on this chip; everything cheaper was
// tried and measured worse.
// ---------------------------------------------------------------------------

#define NBK 160            // max buckets: ceil(80000/512)=157 <= 160
#define HB  256            // edge-pass blocks in pA
#define CAP 9216           // per-bucket slot capacity (mean 8192, +11 sigma)

typedef __attribute__((ext_vector_type(8))) short bf16x8;
typedef __attribute__((ext_vector_type(4))) float f32x4;

__device__ __forceinline__ float bflo(unsigned u) { return __uint_as_float(u << 16); }
__device__ __forceinline__ float bfhi(unsigned u) { return __uint_as_float(u & 0xffff0000u); }
__device__ __forceinline__ float bf1(unsigned short u) { return __uint_as_float((unsigned)u << 16); }
__device__ __forceinline__ unsigned short f2bf(float f) {   // RNE
    unsigned u = __float_as_uint(f);
    return (unsigned short)((u + 0x7fff + ((u >> 16) & 1)) >> 16);
}
__device__ __forceinline__ unsigned packbf(float lo, float hi) {
    return (unsigned)f2bf(lo) | ((unsigned)f2bf(hi) << 16);
}

// --- pA: single-pass bucket scatter (blocks < HB) + graph bounds (rest) ----
__global__ __launch_bounds__(256) void pA_scatter(
    const int* __restrict__ src, const int* __restrict__ dst,
    int* __restrict__ curD, int* __restrict__ curS,       // NBK cursors each, pre-zeroed
    int* __restrict__ pack, unsigned short* __restrict__ sloc,
    const int* __restrict__ gids, int* __restrict__ goffs,
    int E, int NB, int N, int G)
{
    if (blockIdx.x >= HB) {                  // fused bounds_kernel
        int i = (blockIdx.x - HB) * 256 + threadIdx.x;
        if (i >= N) return;
        int b = gids[i];
        if (i == 0) {
            for (int g = 0; g <= b; g++) goffs[g] = 0;
        } else {
            int a = gids[i - 1];
            for (int g = a + 1; g <= b; g++) goffs[g] = i;
        }
        if (i == N - 1) {
            for (int g = b + 1; g <= G; g++) goffs[g] = N;
        }
        return;
    }
    __shared__ int hd[NBK], hs[NBK];
    int t = threadIdx.x;
    for (int i = t; i < NB; i += 256) { hd[i] = 0; hs[i] = 0; }
    __syncthreads();
    int chunk = (E + HB - 1) / HB;
    int s0 = blockIdx.x * chunk, s1 = min(E, s0 + chunk);
    // vectorized histogram pass
    int q0 = s0 >> 2, q1 = s1 >> 2;          // s0 is 4-aligned (chunk%4==0)
    const int4* s4 = (const int4*)src;
    const int4* d4 = (const int4*)dst;
    for (int q = q0 + t; q < q1; q += 256) {
        int4 d = d4[q];
        int4 s = s4[q];
        atomicAdd(&hd[d.x >> 9], 1); atomicAdd(&hd[d.y >> 9], 1);
        atomicAdd(&hd[d.z >> 9], 1); atomicAdd(&hd[d.w >> 9], 1);
        atomicAdd(&hs[s.x >> 9], 1); atomicAdd(&hs[s.y >> 9], 1);
        atomicAdd(&hs[s.z >> 9], 1); atomicAdd(&hs[s.w >> 9], 1);
    }
    for (int i = (q1 << 2) + t; i < s1; i += 256) {   // tail
        atomicAdd(&hd[dst[i] >> 9], 1);
        atomicAdd(&hs[src[i] >> 9], 1);
    }
    __syncthreads();
    for (int b = t; b < NB; b += 256) {      // reserve global slots
        int cd = hd[b], cs = hs[b];
        hd[b] = cd ? atomicAdd(&curD[b], cd) : 0;   // device atomic, 1/bucket
        hs[b] = cs ? atomicAdd(&curS[b], cs) : 0;
    }
    __syncthreads();
    // vectorized scatter pass (chunk re-read is L2-hot)
    for (int q = q0 + t; q < q1; q += 256) {
        int4 d = d4[q];
        int4 s = s4[q];
        #pragma unroll
        for (int j = 0; j < 4; j++) {
            int ss = j == 0 ? s.x : j == 1 ? s.y : j == 2 ? s.z : s.w;
            int dd = j == 0 ? d.x : j == 1 ? d.y : j == 2 ? d.z : d.w;
            int bd = dd >> 9, bs = ss >> 9;
            int pd = atomicAdd(&hd[bd], 1);  // LDS atomic
            int ps = atomicAdd(&hs[bs], 1);  // LDS atomic
            if (pd < CAP) pack[(size_t)bd * CAP + pd] = ((dd & 511) << 17) | ss;
            if (ps < CAP) sloc[(size_t)bs * CAP + ps] = (unsigned short)(ss & 511);
        }
    }
    for (int i = (q1 << 2) + t; i < s1; i += 256) {   // tail
        int s = src[i], d = dst[i];
        int bd = d >> 9, bs = s >> 9;
        int pd = atomicAdd(&hd[bd], 1);
        int ps = atomicAdd(&hs[bs], 1);
        if (pd < CAP) pack[(size_t)bd * CAP + pd] = ((d & 511) << 17) | s;
        if (ps < CAP) sloc[(size_t)bs * CAP + ps] = (unsigned short)(s & 511);
    }
}

// --- p5: dst mode -> CSR (row_offs,deg,col,ndst); src mode -> nsrc+prescale -
__global__ __launch_bounds__(256) void p5_build(
    const int* __restrict__ pack, const unsigned short* __restrict__ sloc,
    const int* __restrict__ curD, const int* __restrict__ curS,
    int* __restrict__ col, int* __restrict__ row_offs, int* __restrict__ deg,
    float* __restrict__ nsrc, float* __restrict__ ndst,
    const float* __restrict__ h, unsigned short* __restrict__ xs,
    int N, int NB)
{
    __shared__ int hist[512];
    __shared__ float nsl[512];
    __shared__ int wt[4];
    int t = threadIdx.x;
    bool dmode = blockIdx.x < NB;
    int b = dmode ? blockIdx.x : blockIdx.x - NB;
    int n0 = b << 9, n1 = min(N, n0 + 512);
    hist[t] = 0; hist[t + 256] = 0;
    __syncthreads();
    int e0 = b * CAP;
    int tot = min(dmode ? curD[b] : curS[b], CAP);
    int e1 = e0 + tot;
    if (!dmode) {
        for (int i = e0 + t; i < e1; i += 256)
            atomicAdd(&hist[sloc[i]], 1);            // LDS atomic
        __syncthreads();
        for (int n = n0 + t; n < n1; n += 256) {
            float s = rsqrtf((float)max(hist[n - n0], 1));
            nsrc[n] = s;
            nsl[n - n0] = s;
        }
        __syncthreads();
        int cnt = n1 - n0;
        const float2* h2p = (const float2*)h;
        ushort2* xp = (ushort2*)xs;
        for (int i = t; i < cnt * 32; i += 256) {
            int node = i >> 5;
            float s = nsl[node];
            float2 v = h2p[(size_t)(n0 + node) * 32 + (i & 31)];
            ushort2 o;
            o.x = f2bf(v.x * s);
            o.y = f2bf(v.y * s);
            xp[(size_t)(n0 + node) * 32 + (i & 31)] = o;
        }
        return;
    }
    for (int i = e0 + t; i < e1; i += 256)
        atomicAdd(&hist[pack[i] >> 17], 1);          // LDS atomic
    __syncthreads();
    int c0 = hist[2 * t], c1 = hist[2 * t + 1];
    int v = c0 + c1;
    int lane = t & 63, w = t >> 6;
    int x = v;
    #pragma unroll
    for (int off = 1; off < 64; off <<= 1) {
        int y = __shfl_up(x, off);
        if (lane >= off) x += y;
    }
    if (lane == 63) wt[w] = x;
    __syncthreads();
    int bw = 0;
    for (int i = 0; i < w; i++) bw += wt[i];
    int excl = x - v + bw;
    int n = n0 + 2 * t;
    if (n < n1) {
        row_offs[n] = e0 + excl;
        deg[n] = c0;
        ndst[n] = rsqrtf((float)max(c0, 1));
    }
    if (n + 1 < n1) {
        row_offs[n + 1] = e0 + excl + c0;
        deg[n + 1] = c1;
        ndst[n + 1] = rsqrtf((float)max(c1, 1));
    }
    hist[2 * t] = excl;
    hist[2 * t + 1] = excl + c0;
    __syncthreads();
    for (int i = e0 + t; i < e1; i += 256) {
        int wd = pack[i];
        int pos = atomicAdd(&hist[wd >> 17], 1);     // LDS atomic
        col[e0 + pos] = wd & 0x1FFFF;
    }
}

// --- pure gather-sum with next-node prefetch (R11-verbatim) ----------------
__global__ __launch_bounds__(256) void agg_kernel(
    const unsigned short* __restrict__ z, unsigned short* __restrict__ y,
    const int* __restrict__ col, const int* __restrict__ row_offs,
    const int* __restrict__ deg, int N)
{
    int lane = threadIdx.x & 63;
    int sub  = lane >> 3;
    int li   = lane & 7;
    const uint4* x4 = (const uint4*)z;

    int wid = (blockIdx.x * 256 + threadIdx.x) >> 6;
    int nw  = (gridDim.x * 256) >> 6;

    int ro = 0, cnt = 0, idx = 0;
    if (wid < N) {
        ro = row_offs[wid];
        cnt = deg[wid];
        if (lane < min(cnt, 64)) idx = col[ro + lane];
    }
    for (int node = wid; node < N; node += nw) {
        int nnode = node + nw;
        int nro = 0, ncnt = 0;
        if (nnode < N) { nro = row_offs[nnode]; ncnt = deg[nnode]; }  // prefetch

        float a0=0.f,a1=0.f,a2=0.f,a3=0.f,a4=0.f,a5=0.f,a6=0.f,a7=0.f;
        int cc = 0;
        int cidx = idx;
        while (cc < cnt) {
            int m = min(cnt - cc, 64);
            for (int i = 0; i < m; i += 32) {
                int e1 = i + sub, e2 = i + 8 + sub, e3 = i + 16 + sub, e4 = i + 24 + sub;
                int s1 = __shfl(cidx, min(e1, m - 1));
                int s2 = __shfl(cidx, min(e2, m - 1));
                int s3 = __shfl(cidx, min(e3, m - 1));
                int s4 = __shfl(cidx, min(e4, m - 1));
                uint4 v1 = make_uint4(0u,0u,0u,0u), v2 = v1, v3 = v1, v4 = v1;
                if (e1 < m) v1 = x4[(size_t)s1 * 8 + li];
                if (e2 < m) v2 = x4[(size_t)s2 * 8 + li];
                if (e3 < m) v3 = x4[(size_t)s3 * 8 + li];
                if (e4 < m) v4 = x4[(size_t)s4 * 8 + li];
                a0 += bflo(v1.x); a1 += bfhi(v1.x);
                a2 += bflo(v1.y); a3 += bfhi(v1.y);
                a4 += bflo(v1.z); a5 += bfhi(v1.z);
                a6 += bflo(v1.w); a7 += bfhi(v1.w);
                a0 += bflo(v2.x); a1 += bfhi(v2.x);
                a2 += bflo(v2.y); a3 += bfhi(v2.y);
                a4 += bflo(v2.z); a5 += bfhi(v2.z);
                a6 += bflo(v2.w); a7 += bfhi(v2.w);
                a0 += bflo(v3.x); a1 += bfhi(v3.x);
                a2 += bflo(v3.y); a3 += bfhi(v3.y);
                a4 += bflo(v3.z); a5 += bfhi(v3.z);
                a6 += bflo(v3.w); a7 += bfhi(v3.w);
                a0 += bflo(v4.x); a1 += bfhi(v4.x);
                a2 += bflo(v4.y); a3 += bfhi(v4.y);
                a4 += bflo(v4.z); a5 += bfhi(v4.z);
                a6 += bflo(v4.w); a7 += bfhi(v4.w);
            }
            cc += 64;
            if (cc < cnt) cidx = (lane < min(cnt - cc, 64)) ? col[ro + cc + lane] : 0;
        }
        // prefetch next node's col during the reduce
        idx = 0;
        if (nnode < N && lane < min(ncnt, 64)) idx = col[nro + lane];

        #pragma unroll
        for (int off = 8; off <= 32; off <<= 1) {
            a0 += __shfl_xor(a0, off); a1 += __shfl_xor(a1, off);
            a2 += __shfl_xor(a2, off); a3 += __shfl_xor(a3, off);
            a4 += __shfl_xor(a4, off); a5 += __shfl_xor(a5, off);
            a6 += __shfl_xor(a6, off); a7 += __shfl_xor(a7, off);
        }
        if (sub == 0) {                       // 8 lanes store the 128B row
            uint4 o;
            o.x = packbf(a0, a1);
            o.y = packbf(a2, a3);
            o.z = packbf(a4, a5);
            o.w = packbf(a6, a7);
            ((uint4*)y)[(size_t)node * 8 + li] = o;
        }
        ro = nro; cnt = ncnt;
    }
}

// --- GEMM + epilogue -------------------------------------------------------
// POOL=0: Z[m] = bf16(relu(ndst[m]*(S[m]@W) + b) * nsrc[m])   (layer 1)
// POOL=1: pooled into gacc[graph][64]; wave-level pre-reduction (gids sorted:
//         one atomic per (wave,col) for single-graph waves; per-element
//         fallback at boundaries). NO fence, NO ticket.
template<int POOL>
__global__ __launch_bounds__(256) void gemm_kernel(
    const unsigned short* __restrict__ A, const float* __restrict__ W,
    const float* __restrict__ b, const float* __restrict__ ndst,
    const float* __restrict__ nsrc, unsigned short* __restrict__ Z,
    const int* __restrict__ gids, float* __restrict__ gacc, int M)
{
    int t = threadIdx.x, lane = t & 63, w = t >> 6;
    int col = lane & 15, quad = lane >> 4;
    bf16x8 bfrag[4][2];
    #pragma unroll
    for (int nt = 0; nt < 4; nt++)
        #pragma unroll
        for (int ks = 0; ks < 2; ks++)
            #pragma unroll
            for (int j = 0; j < 8; j++)
                bfrag[nt][ks][j] =
                    (short)f2bf(W[(ks * 32 + quad * 8 + j) * 64 + nt * 16 + col]);
    float bias[4];
    #pragma unroll
    for (int nt = 0; nt < 4; nt++) bias[nt] = b[nt * 16 + col];

    int mbase = blockIdx.x * 64 + w * 16;
    if (mbase >= M) return;                    // whole-wave exit, no barriers
    int row = min(mbase + col, M - 1);
    const uint4* a4 = (const uint4*)A;
    union { uint4 u; bf16x8 v; } a0, a1;
    a0.u = a4[(size_t)row * 8 + quad];
    a1.u = a4[(size_t)row * 8 + 4 + quad];

    float nd[4], ns[4];
    int gg[4];
    #pragma unroll
    for (int r = 0; r < 4; r++) {
        int m = min(mbase + quad * 4 + r, M - 1);
        nd[r] = ndst[m];
        ns[r] = POOL ? 1.f : nsrc[m];
        gg[r] = POOL ? gids[m] : 0;
    }
    bool uni = false;
    int g0 = 0;
    if (POOL) {
        g0 = gids[min(mbase, M - 1)];
        uni = (g0 == gids[min(mbase + 15, M - 1)]) && (mbase + 15 < M);
    }

    #pragma unroll
    for (int nt = 0; nt < 4; nt++) {
        f32x4 acc = {0.f, 0.f, 0.f, 0.f};
        acc = __builtin_amdgcn_mfma_f32_16x16x32_bf16(a0.v, bfrag[nt][0], acc, 0, 0, 0);
        acc = __builtin_amdgcn_mfma_f32_16x16x32_bf16(a1.v, bfrag[nt][1], acc, 0, 0, 0);
        if (POOL) {
            float vv[4];
            #pragma unroll
            for (int r = 0; r < 4; r++) {
                int m = mbase + quad * 4 + r;
                vv[r] = (m < M) ? fmaxf(nd[r] * acc[r] + bias[nt], 0.f) : 0.f;
            }
            if (uni) {                       // 16 rows, one graph: 1 atomic/col
                float s = (vv[0] + vv[1]) + (vv[2] + vv[3]);
                s += __shfl_xor(s, 16);
                s += __shfl_xor(s, 32);
                if (quad == 0)
                    atomicAdd(&gacc[(size_t)g0 * 64 + nt * 16 + col], s);
            } else {                         // boundary wave (rare)
                #pragma unroll
                for (int r = 0; r < 4; r++) {
                    int m = mbase + quad * 4 + r;
                    if (m < M)
                        atomicAdd(&gacc[(size_t)gg[r] * 64 + nt * 16 + col], vv[r]);
                }
            }
        } else {
            #pragma unroll
            for (int r = 0; r < 4; r++) {
                int m = mbase + quad * 4 + r;
                if (m < M) {
                    float v = fmaxf(nd[r] * acc[r] + bias[nt], 0.f);
                    Z[(size_t)m * 64 + nt * 16 + col] = f2bf(v * ns[r]);
                }
            }
        }
    }
}

// --- per-graph mean + 64x5 classifier (1 wave per graph) -------------------
__global__ __launch_bounds__(64) void cls_kernel(
    const float* __restrict__ gacc, const int* __restrict__ goffs,
    const float* __restrict__ Wc, const float* __restrict__ bc,
    float* __restrict__ out, int G)
{
    int g = blockIdx.x;
    int lane = threadIdx.x;
    float cnt = (float)max(goffs[g + 1] - goffs[g], 1);
    float mean = gacc[(size_t)g * 64 + lane] / cnt;
    #pragma unroll
    for (int c = 0; c < 5; c++) {
        float p = mean * Wc[lane * 5 + c];
        #pragma unroll
        for (int off = 32; off; off >>= 1) p += __shfl_down(p, off);
        if (lane == 0) out[g * 5 + c] = p + bc[c];
    }
}

extern "C" void kernel_launch(void* const* d_in, const int* in_sizes, int n_in,
                              void* d_out, int out_size, void* d_ws, size_t ws_size,
                              hipStream_t stream)
{
    const float* h    = (const float*)d_in[0];
    const int*   src  = (const int*)d_in[1];
    const int*   dst  = (const int*)d_in[2];
    const int*   gids = (const int*)d_in[3];
    const float* W1   = (const float*)d_in[4];
    const float* b1   = (const float*)d_in[5];
    const float* W2   = (const float*)d_in[6];
    const float* b2   = (const float*)d_in[7];
    const float* Wc   = (const float*)d_in[8];
    const float* bc   = (const float*)d_in[9];
    float* out = (float*)d_out;

    const int N = in_sizes[0] / 64;
    const int E = in_sizes[1];
    const int G = out_size / 5;
    const int NB = (N + 511) >> 9;
    const int NBB = (N + 255) / 256;        // bounds blocks

    auto align = [](size_t x) { return (x + 255) & ~(size_t)255; };
    char* p = (char*)d_ws;
    // curD | curS | gacc contiguous -> single memset clears all three
    int* curD    = (int*)p;
    int* curS    = curD + NBK;
    float* gacc  = (float*)(p + (size_t)2 * NBK * 4);   // G*64 floats
    size_t zbytes = (size_t)2 * NBK * 4 + (size_t)G * 64 * 4;
    p += align(zbytes);
    int* row_offs= (int*)p;            p += align((size_t)N * 4);
    int* deg     = (int*)p;            p += align((size_t)N * 4);
    float* nsrc  = (float*)p;          p += align((size_t)N * 4);
    float* ndst  = (float*)p;          p += align((size_t)N * 4);
    int* goffs   = (int*)p;            p += align((size_t)(G + 1) * 4);
    int* pack    = (int*)p;            p += align((size_t)NBK * CAP * 4);
    unsigned short* sloc = (unsigned short*)p; p += align((size_t)NBK * CAP * 2);
    int* cols    = (int*)p;            p += align((size_t)NBK * CAP * 4);
    unsigned short* xs  = (unsigned short*)p; p += align((size_t)N * 64 * 2);
    unsigned short* s1  = (unsigned short*)p; p += align((size_t)N * 64 * 2);
    unsigned short* h1s = (unsigned short*)p; p += align((size_t)N * 64 * 2);
    unsigned short* s2  = s1;   // alias: s1 dead after gemm1

    hipMemsetAsync(curD, 0, zbytes, stream);

    pA_scatter<<<HB + NBB, 256, 0, stream>>>(src, dst, curD, curS, pack, sloc,
                                             gids, goffs, E, NB, N, G);
    p5_build<<<2 * NB, 256, 0, stream>>>(pack, sloc, curD, curS, cols,
                                         row_offs, deg, nsrc, ndst, h, xs, N, NB);

    agg_kernel<<<4096, 256, 0, stream>>>(xs, s1, cols, row_offs, deg, N);
    gemm_kernel<0><<<(N + 63) / 64, 256, 0, stream>>>(s1, W1, b1, ndst, nsrc,
                                                      h1s, nullptr, nullptr, N);
    agg_kernel<<<4096, 256, 0, stream>>>(h1s, s2, cols, row_offs, deg, N);
    gemm_kernel<1><<<(N + 63) / 64, 256, 0, stream>>>(s2, W2, b2, ndst, nullptr,
                                                      nullptr, gids, gacc, N);
    cls_kernel<<<G, 64, 0, stream>>>(gacc, goffs, Wc, bc, out, G);
}